// Round 1
// 187.812 us; speedup vs baseline: 1.1259x; 1.1259x over previous
//
#include <hip/hip_runtime.h>
#include <stdint.h>

#define B_ 64
#define T_ 4096
#define D_ 90
#define K_ 32
#define CH_ 32   // chunk length (one wave's emission tile == one chunk)
#define F_  128  // number of T-chunks = T_/CH_

typedef float f32x16 __attribute__((ext_vector_type(16)));
typedef __bf16 bf16x8 __attribute__((ext_vector_type(8)));

// ---- workspace layout (float offsets). total ~17.9 MB ----
#define WS_A     0          // 1024 : softmax(transition) rows, A[j*32+k]
#define WS_PI    1024       // 32   : softmax(priors)
#define WS_C0    1056       // 32   : per-state emission constant
#define WS_WF    1088       // 6144 bf16 : MFMA B-fragments of emission weights
#define WS_EACC  4160       // 8192 ints : per-(b,chunk) renorm exponent
#define WS_MS    12352      // 8192 : per-wave msum slots
#define WS_E0    20544      // 2048 bf16 : E[b][k][t=0] for the alpha0 term
#define WS_PE    21568      // 512 ints : stage-1 partial exponents
#define WS_PM    22080      // 524288 bf16 : stage-1 partial matrices (A-frag truncated)
#define WS_Q     284224     // 8388608 bf16 : Q[b][c][k_new][j_old], A-frag truncated

// block-swap involution: swap 4-7<->8-11 and 20-23<->24-27
__device__ __forceinline__ int perm_r(int r) {
  int t2 = (r >> 2) & 3;
  return r + ((t2 == 1) ? 4 : (t2 == 2) ? -4 : 0);
}
// pack two f32 -> bf16x2 dword, truncation — single v_perm_b32
__device__ __forceinline__ uint32_t pk2(float hi, float lo) {
  return __builtin_amdgcn_perm(__float_as_uint(hi), __float_as_uint(lo), 0x07060302u);
}
// round-to-nearest variant (emission path)
__device__ __forceinline__ uint32_t rnd_pk(float hi, float lo) {
  uint32_t uh = __float_as_uint(hi) + 0x8000u;
  uint32_t ul = __float_as_uint(lo) + 0x8000u;
  return __builtin_amdgcn_perm(uh, ul, 0x07060302u);
}
__device__ __forceinline__ float bf2f(ushort u) {
  return __uint_as_float(((uint32_t)u) << 16);
}
__device__ __forceinline__ bf16x8 mkbf(uint32_t a, uint32_t b, uint32_t c, uint32_t d) {
  union { uint32_t u[4]; bf16x8 v; } x;
  x.u[0] = a; x.u[1] = b; x.u[2] = c; x.u[3] = d;
  return x.v;
}

// ---------------- prep: softmaxes + emission weight fragments ----------------
__global__ __launch_bounds__(1024) void prep_kernel(
    const float* __restrict__ priors, const float* __restrict__ trans,
    const float* __restrict__ mu, const float* __restrict__ lv,
    float* __restrict__ ws) {
  int tid = threadIdx.x;
  {  // transition row softmax: tid = j*32+k, 32-lane groups are rows
    float v = trans[tid];
    float m = v;
    #pragma unroll
    for (int mk = 16; mk; mk >>= 1) m = fmaxf(m, __shfl_xor(m, mk));
    float e = expf(v - m);
    float s = e;
    #pragma unroll
    for (int mk = 16; mk; mk >>= 1) s += __shfl_xor(s, mk);
    ws[WS_A + tid] = e / s;
  }
  if (tid < 32) {  // prior softmax
    float v = priors[tid];
    float m = v;
    #pragma unroll
    for (int mk = 16; mk; mk >>= 1) m = fmaxf(m, __shfl_xor(m, mk));
    float e = expf(v - m);
    float s = e;
    #pragma unroll
    for (int mk = 16; mk; mk >>= 1) s += __shfl_xor(s, mk);
    ws[WS_PI + tid] = e / s;
  }
  // MFMA B-operand weight fragments, bf16, layout [c][mat][lane][j]
  for (int i = tid; i < 6144; i += 1024) {
    int j = i & 7, l = (i >> 3) & 63, cm = i >> 9;
    int c = cm >> 1, mat = cm & 1;
    int h = l >> 5, nn = l & 31;
    int d = 16 * c + 8 * h + j;
    float v = 0.0f;
    if (d < D_) {
      float ivd = expf(-lv[nn * D_ + d]);
      v = (mat == 0) ? -0.5f * ivd : mu[nn * D_ + d] * ivd;
    }
    ((ushort*)(ws + WS_WF))[i] = (ushort)((__float_as_uint(v) + 0x8000u) >> 16);
  }
  if (tid < 32) {  // c0[k] = -0.5*(sum mu^2*iv + sum lv + D*log(2pi))
    float s = 0.0f;
    for (int d = 0; d < D_; ++d) {
      float l  = lv[tid * D_ + d];
      float iv = expf(-l);
      float m_ = mu[tid * D_ + d];
      s += m_ * m_ * iv + l;
    }
    ws[WS_C0 + tid] = -0.5f * (s + (float)D_ * 1.8378770664093453f);
  }
}

// ---------------- fused: emission MFMA -> E in LDS -> chunk recursion ----------------
// Block = 128 consecutive t of one b; wave w owns 32 t = exactly one chunk.
// E never touches HBM. X staged as bf16 (rows padded 90->104, 16B-aligned b128 reads);
// MFMA A-input was bf16(x) already, only the x^2 operand now squares the bf16 value.
__global__ __launch_bounds__(256, 3) void fused_kernel(const float* __restrict__ X,
                                                       float* __restrict__ ws) {
  __shared__ ushort xsb[4][32 * 104];  // 26.6 KB : bf16 X rows per wave region
  __shared__ ushort els[4][32 * 40];   // 10.0 KB : E[k][t] per wave, stride 40 (4-way max)
  int tid = threadIdx.x;
  int l = tid & 63, w = tid >> 6;
  int n = l & 31, h = l >> 5;
  int tB = blockIdx.x << 7;
  // ---- stage X as rounded bf16 (pairs never straddle rows: 90 is even) ----
  const float4* Xg = (const float4*)(X + (size_t)tB * D_);
  #pragma unroll
  for (int it = 0; it < 12; ++it) {
    int i = tid + (it << 8);
    if (i < 2880) {
      float4 v = Xg[i];
      int g = i / 720;
      int f = (i - g * 720) * 4;          // float index within 32-row group
      uint32_t d0 = rnd_pk(v.y, v.x);
      uint32_t d1 = rnd_pk(v.w, v.z);
      int r0 = f / 90;        int c0_ = f - r0 * 90;
      int r1 = (f + 2) / 90;  int c1_ = (f + 2) - r1 * 90;
      *(uint32_t*)&xsb[g][r0 * 104 + c0_] = d0;
      *(uint32_t*)&xsb[g][r1 * 104 + c1_] = d1;
    }
  }
  for (int i = tid; i < 896; i += 256) {  // zero the d=90..103 pad (weights are 0 there,
    int r = i / 7;                        // but garbage bf16 could be NaN: NaN*0=NaN)
    int d = 90 + 2 * (i - r * 7);
    *(uint32_t*)&xsb[r >> 5][(r & 31) * 104 + d] = 0u;
  }
  const uint4* wfp = (const uint4*)((const ushort*)(ws + WS_WF));
  uint4 wf[12];
  #pragma unroll
  for (int cm = 0; cm < 12; ++cm) wf[cm] = wfp[cm * 64 + l];   // coalesced b128
  float c0 = ws[WS_C0 + n];
  __syncthreads();

  int t0 = tB + (w << 5);
  int b  = t0 >> 12;
  int bc = t0 >> 5;                       // global chunk index = b*128 + c
  const ushort* xrow = &xsb[w][n * 104];  // A-row m = n
  f32x16 acc1, acc2;
  #pragma unroll
  for (int r = 0; r < 16; ++r) { acc1[r] = 0.0f; acc2[r] = 0.0f; }
  #pragma unroll
  for (int c = 0; c < 6; ++c) {
    union { uint4 u; bf16x8 v; } xb;
    xb.u = *(const uint4*)(xrow + 16 * c + 8 * h);   // b128, A-frag ready
    float x[8];
    #pragma unroll
    for (int j = 0; j < 8; ++j) {
      uint32_t uu = ((const uint32_t*)&xb.u)[j >> 1];
      x[j] = bf2f((j & 1) ? (ushort)(uu >> 16) : (ushort)(uu & 0xFFFF));
    }
    union { uint32_t u[4]; bf16x8 v; } x2b;
    #pragma unroll
    for (int r = 0; r < 4; ++r)
      x2b.u[r] = rnd_pk(x[2*r+1] * x[2*r+1], x[2*r] * x[2*r]);
    union { uint4 u; bf16x8 v; } w2, w1;
    w2.u = wf[c * 2]; w1.u = wf[c * 2 + 1];
    acc1 = __builtin_amdgcn_mfma_f32_32x32x16_bf16(xb.v,  w1.v, acc1, 0, 0, 0);
    acc2 = __builtin_amdgcn_mfma_f32_32x32x16_bf16(x2b.v, w2.v, acc2, 0, 0, 0);
  }
  // C/D: col k = n, row t = (r&3) + 8*(r>>2) + 4*h
  float em[16], mrow[16];
  #pragma unroll
  for (int r = 0; r < 16; ++r) {
    float v = acc1[r] + acc2[r] + c0;
    em[r] = v;
    float m = v;
    #pragma unroll
    for (int mk = 1; mk <= 16; mk <<= 1) m = fmaxf(m, __shfl_xor(m, mk));  // max over k
    mrow[r] = m;
  }
  ushort* Ew = els[w];                    // E[k=n][t], stride 40
  #pragma unroll
  for (int q = 0; q < 4; ++q) {
    float e0 = exp2f((em[4*q]   - mrow[4*q])   * 1.44269504088896f);
    float e1 = exp2f((em[4*q+1] - mrow[4*q+1]) * 1.44269504088896f);
    float e2 = exp2f((em[4*q+2] - mrow[4*q+2]) * 1.44269504088896f);
    float e3 = exp2f((em[4*q+3] - mrow[4*q+3]) * 1.44269504088896f);
    uint2 d;
    d.x = rnd_pk(e1, e0);
    d.y = rnd_pk(e3, e2);
    *(uint2*)(Ew + n * 40 + 8 * q + 4 * h) = d;
    if (q == 0 && h == 0 && (t0 & (T_ - 1)) == 0)   // export E[b][k][0] for alpha0
      ((ushort*)(ws + WS_E0))[b * K_ + n] = (ushort)(d.x & 0xFFFF);
  }
  float msum = 0.0f;
  #pragma unroll
  for (int r = 0; r < 16; ++r) msum += mrow[r];
  msum += __shfl_xor(msum, 32);
  if (l == 0) ws[WS_MS + bc] = msum;
  __syncthreads();                        // E writes visible (also orders LDS within wave)

  // ---- chunk recursion (wave-local E from LDS) ----
  int col = perm_r(n);                    // logical output-state of this lane's A column
  const float* A = ws + WS_A;
  float astat[16];
  #pragma unroll
  for (int j = 0; j < 8; ++j) {
    astat[j]     = A[(8 * h + j) * K_ + col];
    astat[8 + j] = A[(16 + 8 * h + j) * K_ + col];
  }
  uint32_t q[8];                          // Q fragments (bf16x2 dwords), init = I
  #pragma unroll
  for (int r = 0; r < 4; ++r) {
    int s0 = 8 * h + 2 * r;
    uint32_t lo = (s0 == n)     ? 0x3F80u : 0u;
    uint32_t hi = (s0 + 1 == n) ? 0x3F80u : 0u;
    q[r] = lo | (hi << 16);
    int s2 = s0 + 16;
    lo = (s2 == n)     ? 0x3F80u : 0u;
    hi = (s2 + 1 == n) ? 0x3F80u : 0u;
    q[4 + r] = lo | (hi << 16);
  }
  int eacc = 0;
  const f32x16 z = {0.f,0.f,0.f,0.f,0.f,0.f,0.f,0.f,0.f,0.f,0.f,0.f,0.f,0.f,0.f,0.f};
  f32x16 acc;
  #pragma unroll
  for (int r = 0; r < 16; ++r) acc[r] = 0.0f;

  auto step = [&](float e0) {
    uint32_t au[8];
    #pragma unroll
    for (int r = 0; r < 4; ++r) {         // A-frag = astat * E[col], truncated to bf16
      au[r]     = pk2(astat[2 * r + 1] * e0, astat[2 * r] * e0);
      au[4 + r] = pk2(astat[8 + 2 * r + 1] * e0, astat[8 + 2 * r] * e0);
    }
    bf16x8 alo = mkbf(au[0], au[1], au[2], au[3]);
    bf16x8 ahi = mkbf(au[4], au[5], au[6], au[7]);
    bf16x8 qlo = mkbf(q[0], q[1], q[2], q[3]);
    bf16x8 qhi = mkbf(q[4], q[5], q[6], q[7]);
    acc = __builtin_amdgcn_mfma_f32_32x32x16_bf16(alo, qlo, z, 0, 0, 0);
    acc = __builtin_amdgcn_mfma_f32_32x32x16_bf16(ahi, qhi, acc, 0, 0, 0);
    #pragma unroll
    for (int r = 0; r < 4; ++r) {         // D regs -> next B-frag, in-lane repack only
      q[r]     = pk2(acc[2 * r + 1], acc[2 * r]);
      q[4 + r] = pk2(acc[8 + 2 * r + 1], acc[8 + 2 * r]);
    }
  };
  auto renorm = [&]() {                   // exact power-of-2 renormalization
    float m = acc[0];
    #pragma unroll
    for (int r = 1; r < 16; ++r) m = fmaxf(m, acc[r]);
    #pragma unroll
    for (int mk = 1; mk <= 32; mk <<= 1) m = fmaxf(m, __shfl_xor(m, mk));
    int ex;
    frexpf(m, &ex);
    float sc = ldexpf(1.0f, -ex);
    eacc += ex;
    #pragma unroll
    for (int r = 0; r < 16; ++r) acc[r] *= sc;
    #pragma unroll
    for (int r = 0; r < 4; ++r) {
      q[r]     = pk2(acc[2 * r + 1], acc[2 * r]);
      q[4 + r] = pk2(acc[8 + 2 * r + 1], acc[8 + 2 * r]);
    }
  };

  const ushort* Eb = els[w] + col * 40;
  int g0 = 0;
  if ((t0 & (T_ - 1)) == 0) {             // t=0 is the prior step: skip it
    uint4 ev = *(const uint4*)(Eb);
    #pragma unroll
    for (int j = 1; j < 8; ++j) {
      uint32_t u = ((const uint32_t*)&ev)[j >> 1];
      step(bf2f((j & 1) ? (ushort)(u >> 16) : (ushort)(u & 0xFFFF)));
    }
    renorm();
    g0 = 1;
  }
  for (int g = g0; g < CH_ / 8; ++g) {
    uint4 ev = *(const uint4*)(Eb + 8 * g);
    #pragma unroll
    for (int j = 0; j < 8; ++j) {
      uint32_t u = ((const uint32_t*)&ev)[j >> 1];
      step(bf2f((j & 1) ? (ushort)(u >> 16) : (ushort)(u & 0xFFFF)));
    }
    renorm();
  }
  // store Q as bf16 TRUNCATED == the pk2 the old combine applied: bit-identical inputs
  ushort* Qo = (ushort*)(ws + WS_Q) + (size_t)bc * (K_ * K_);
  #pragma unroll
  for (int r = 0; r < 16; ++r) {          // row = pi(physical row), col = n
    int m_ = (r & 3) + 8 * (r >> 2) + 4 * h;
    Qo[perm_r(m_) * K_ + n] = (ushort)(__float_as_uint(acc[r]) >> 16);
  }
  if (l == 0) ((int*)ws)[WS_EACC + bc] = eacc;
}

// ---------------- combine stage 1: 512 one-wave blocks (spread Q read over all CUs) ----
__global__ __launch_bounds__(64) void combine1_kernel(float* __restrict__ ws) {
  int l = threadIdx.x;
  int h = l >> 5, n = l & 31;
  int bw = blockIdx.x;                    // b*8 + w
  int b = bw >> 3, w = bw & 7;
  int row = perm_r(n);
  const ushort* Qb = (const ushort*)(ws + WS_Q) + (size_t)(b * F_ + w * 16) * (K_ * K_);
  int eacc;
  {
    const int* ea = ((const int*)ws) + WS_EACC + b * F_ + w * 16;
    int v = (l < 16) ? ea[l] : 0;
    #pragma unroll
    for (int mk = 1; mk <= 8; mk <<= 1) v += __shfl_xor(v, mk);
    eacc = __shfl(v, 0);
  }
  uint32_t q[8];                          // B-frag = identity
  #pragma unroll
  for (int r = 0; r < 4; ++r) {
    int s0 = 8 * h + 2 * r;
    uint32_t lo = (s0 == n)     ? 0x3F80u : 0u;
    uint32_t hi = (s0 + 1 == n) ? 0x3F80u : 0u;
    q[r] = lo | (hi << 16);
    int s2 = s0 + 16;
    lo = (s2 == n)     ? 0x3F80u : 0u;
    hi = (s2 + 1 == n) ? 0x3F80u : 0u;
    q[4 + r] = lo | (hi << 16);
  }
  f32x16 acc;
  #pragma unroll
  for (int r = 0; r < 16; ++r) acc[r] = 0.0f;
  const f32x16 z = {0.f,0.f,0.f,0.f,0.f,0.f,0.f,0.f,0.f,0.f,0.f,0.f,0.f,0.f,0.f,0.f};

  auto lmul = [&](uint4 lo, uint4 hi) {   // A-frags come straight from memory (bf16)
    bf16x8 alo = mkbf(lo.x, lo.y, lo.z, lo.w);
    bf16x8 ahi = mkbf(hi.x, hi.y, hi.z, hi.w);
    bf16x8 qlo = mkbf(q[0], q[1], q[2], q[3]);
    bf16x8 qhi = mkbf(q[4], q[5], q[6], q[7]);
    acc = __builtin_amdgcn_mfma_f32_32x32x16_bf16(alo, qlo, z, 0, 0, 0);
    acc = __builtin_amdgcn_mfma_f32_32x32x16_bf16(ahi, qhi, acc, 0, 0, 0);
    #pragma unroll
    for (int r = 0; r < 4; ++r) {
      q[r]     = pk2(acc[2 * r + 1], acc[2 * r]);
      q[4 + r] = pk2(acc[8 + 2 * r + 1], acc[8 + 2 * r]);
    }
  };
  auto renorm = [&]() {
    float m = acc[0];
    #pragma unroll
    for (int r = 1; r < 16; ++r) m = fmaxf(m, acc[r]);
    #pragma unroll
    for (int mk = 1; mk <= 32; mk <<= 1) m = fmaxf(m, __shfl_xor(m, mk));
    int ex;
    frexpf(m, &ex);
    float sc = ldexpf(1.0f, -ex);
    eacc += ex;
    #pragma unroll
    for (int r = 0; r < 16; ++r) acc[r] *= sc;
    #pragma unroll
    for (int r = 0; r < 4; ++r) {
      q[r]     = pk2(acc[2 * r + 1], acc[2 * r]);
      q[4 + r] = pk2(acc[8 + 2 * r + 1], acc[8 + 2 * r]);
    }
  };

  uint4 rlo[4], rhi[4];                   // depth-4 prefetch ring, static indices only
  #pragma unroll
  for (int p = 0; p < 4; ++p) {
    const ushort* Mc = Qb + (size_t)p * (K_ * K_) + row * K_;
    rlo[p] = *(const uint4*)(Mc + 8 * h);
    rhi[p] = *(const uint4*)(Mc + 16 + 8 * h);
  }
  #pragma unroll
  for (int c = 0; c < 16; ++c) {          // ascending c => later chunks on the left
    lmul(rlo[c & 3], rhi[c & 3]);
    if (c + 4 < 16) {
      const ushort* Mc = Qb + (size_t)(c + 4) * (K_ * K_) + row * K_;
      rlo[c & 3] = *(const uint4*)(Mc + 8 * h);
      rhi[c & 3] = *(const uint4*)(Mc + 16 + 8 * h);
    }
    if ((c & 3) == 3) renorm();
  }
  // publish partial product, bf16 A-frag truncated (bit-identical to old pk2-in-lmul)
  ushort* pmq = (ushort*)(ws + WS_PM) + (size_t)bw * (K_ * K_);
  #pragma unroll
  for (int r = 0; r < 16; ++r) {
    int m_ = (r & 3) + 8 * (r >> 2) + 4 * h;
    pmq[perm_r(m_) * K_ + n] = (ushort)(__float_as_uint(acc[r]) >> 16);
  }
  if (l == 0) ((int*)ws)[WS_PE + bw] = eacc;
}

// ---------------- combine stage 2: compose 8 partials per b + alpha0 ----------------
__global__ __launch_bounds__(64) void combine2_kernel(float* __restrict__ ws,
                                                      float* __restrict__ out) {
  int l = threadIdx.x;
  int h = l >> 5, n = l & 31;
  int b = blockIdx.x;
  int row = perm_r(n);
  float alpha0 = ws[WS_PI + n] * bf2f(((const ushort*)(ws + WS_E0))[b * K_ + n]);
  float msm = ws[WS_MS + b * 128 + l] + ws[WS_MS + b * 128 + 64 + l];
  uint32_t q[8];
  #pragma unroll
  for (int r = 0; r < 4; ++r) {
    int s0 = 8 * h + 2 * r;
    uint32_t lo = (s0 == n)     ? 0x3F80u : 0u;
    uint32_t hi = (s0 + 1 == n) ? 0x3F80u : 0u;
    q[r] = lo | (hi << 16);
    int s2 = s0 + 16;
    lo = (s2 == n)     ? 0x3F80u : 0u;
    hi = (s2 + 1 == n) ? 0x3F80u : 0u;
    q[4 + r] = lo | (hi << 16);
  }
  f32x16 acc;
  #pragma unroll
  for (int r = 0; r < 16; ++r) acc[r] = 0.0f;
  const f32x16 z = {0.f,0.f,0.f,0.f,0.f,0.f,0.f,0.f,0.f,0.f,0.f,0.f,0.f,0.f,0.f,0.f};
  const ushort* pmq = (const ushort*)(ws + WS_PM) + (size_t)b * 8 * (K_ * K_);
  #pragma unroll
  for (int p = 0; p < 8; ++p) {           // no renorm: drift <= 2^±40, fp32-safe
    const ushort* base = pmq + p * (K_ * K_) + row * K_;
    uint4 lo = *(const uint4*)(base + 8 * h);
    uint4 hi = *(const uint4*)(base + 16 + 8 * h);
    bf16x8 alo = mkbf(lo.x, lo.y, lo.z, lo.w);
    bf16x8 ahi = mkbf(hi.x, hi.y, hi.z, hi.w);
    bf16x8 qlo = mkbf(q[0], q[1], q[2], q[3]);
    bf16x8 qhi = mkbf(q[4], q[5], q[6], q[7]);
    acc = __builtin_amdgcn_mfma_f32_32x32x16_bf16(alo, qlo, z, 0, 0, 0);
    acc = __builtin_amdgcn_mfma_f32_32x32x16_bf16(ahi, qhi, acc, 0, 0, 0);
    #pragma unroll
    for (int r = 0; r < 4; ++r) {
      q[r]     = pk2(acc[2 * r + 1], acc[2 * r]);
      q[4 + r] = pk2(acc[8 + 2 * r + 1], acc[8 + 2 * r]);
    }
  }
  int et = (l < 8) ? ((const int*)ws)[WS_PE + b * 8 + l] : 0;
  #pragma unroll
  for (int mk = 1; mk <= 4; mk <<= 1) et += __shfl_xor(et, mk);
  et = __shfl(et, 0);
  // ssum = sum_{k,j} Qtot[k][j] * alpha0[j]; lane holds col n, rows across (r,h)
  float part = 0.0f;
  #pragma unroll
  for (int r = 0; r < 16; ++r) part += acc[r];
  part *= alpha0;
  #pragma unroll
  for (int mk = 1; mk <= 32; mk <<= 1) part += __shfl_xor(part, mk);
  #pragma unroll
  for (int mk = 32; mk; mk >>= 1) msm += __shfl_xor(msm, mk);
  if (l == 0) {
    float res = logf(part) + (float)et * 0.69314718055994531f + msm;
    atomicAdd(out, res);
  }
}

extern "C" void kernel_launch(void* const* d_in, const int* in_sizes, int n_in,
                              void* d_out, int out_size, void* d_ws, size_t ws_size,
                              hipStream_t stream) {
  (void)in_sizes; (void)n_in; (void)out_size; (void)ws_size;
  const float* X      = (const float*)d_in[0];
  const float* priors = (const float*)d_in[1];
  const float* trans  = (const float*)d_in[2];
  const float* mu     = (const float*)d_in[3];
  const float* lv     = (const float*)d_in[4];
  float* ws  = (float*)d_ws;
  float* out = (float*)d_out;
  hipMemsetAsync(out, 0, sizeof(float), stream);
  prep_kernel<<<1, 1024, 0, stream>>>(priors, trans, mu, lv, ws);
  fused_kernel<<<B_ * T_ / 128, 256, 0, stream>>>(X, ws);
  combine1_kernel<<<B_ * 8, 64, 0, stream>>>(ws);
  combine2_kernel<<<B_, 64, 0, stream>>>(ws, out);
}

// Round 2
// 185.691 us; speedup vs baseline: 1.1388x; 1.0114x over previous
//
#include <hip/hip_runtime.h>
#include <stdint.h>

#define B_ 64
#define T_ 4096
#define D_ 90
#define K_ 32
#define CH_ 32   // chunk length (one wave's emission tile == one chunk)
#define F_  128  // number of T-chunks = T_/CH_

typedef float f32x16 __attribute__((ext_vector_type(16)));
typedef __bf16 bf16x8 __attribute__((ext_vector_type(8)));

// ---- workspace layout (float offsets). total ~17.9 MB ----
#define WS_A     0          // 1024 : softmax(transition) rows, A[j*32+k]
#define WS_PI    1024       // 32   : softmax(priors)
#define WS_C0    1056       // 32   : per-state emission constant
#define WS_WF    1088       // 6144 bf16 : MFMA B-fragments of emission weights
#define WS_EACC  4160       // 8192 ints : per-(b,chunk) renorm exponent
#define WS_MS    12352      // 8192 : per-wave msum slots
#define WS_E0    20544      // 2048 bf16 : E[b][k][t=0] for the alpha0 term
#define WS_PE    21568      // 512 ints : stage-1 partial exponents
#define WS_PM    22080      // 524288 bf16 : stage-1 partial matrices (A-frag truncated)
#define WS_Q     284224     // 8388608 bf16 : Q[b][c][k_new][j_old], A-frag truncated

// block-swap involution: swap 4-7<->8-11 and 20-23<->24-27
__device__ __forceinline__ int perm_r(int r) {
  int t2 = (r >> 2) & 3;
  return r + ((t2 == 1) ? 4 : (t2 == 2) ? -4 : 0);
}
// pack two f32 -> bf16x2 dword, truncation — single v_perm_b32
__device__ __forceinline__ uint32_t pk2(float hi, float lo) {
  return __builtin_amdgcn_perm(__float_as_uint(hi), __float_as_uint(lo), 0x07060302u);
}
// round-to-nearest variant (emission path)
__device__ __forceinline__ uint32_t rnd_pk(float hi, float lo) {
  uint32_t uh = __float_as_uint(hi) + 0x8000u;
  uint32_t ul = __float_as_uint(lo) + 0x8000u;
  return __builtin_amdgcn_perm(uh, ul, 0x07060302u);
}
__device__ __forceinline__ float bf2f(ushort u) {
  return __uint_as_float(((uint32_t)u) << 16);
}
__device__ __forceinline__ bf16x8 mkbf(uint32_t a, uint32_t b, uint32_t c, uint32_t d) {
  union { uint32_t u[4]; bf16x8 v; } x;
  x.u[0] = a; x.u[1] = b; x.u[2] = c; x.u[3] = d;
  return x.v;
}

// ---------------- prep: softmaxes + emission weight fragments ----------------
__global__ __launch_bounds__(1024) void prep_kernel(
    const float* __restrict__ priors, const float* __restrict__ trans,
    const float* __restrict__ mu, const float* __restrict__ lv,
    float* __restrict__ ws) {
  int tid = threadIdx.x;
  {  // transition row softmax: tid = j*32+k, 32-lane groups are rows
    float v = trans[tid];
    float m = v;
    #pragma unroll
    for (int mk = 16; mk; mk >>= 1) m = fmaxf(m, __shfl_xor(m, mk));
    float e = expf(v - m);
    float s = e;
    #pragma unroll
    for (int mk = 16; mk; mk >>= 1) s += __shfl_xor(s, mk);
    ws[WS_A + tid] = e / s;
  }
  if (tid < 32) {  // prior softmax
    float v = priors[tid];
    float m = v;
    #pragma unroll
    for (int mk = 16; mk; mk >>= 1) m = fmaxf(m, __shfl_xor(m, mk));
    float e = expf(v - m);
    float s = e;
    #pragma unroll
    for (int mk = 16; mk; mk >>= 1) s += __shfl_xor(s, mk);
    ws[WS_PI + tid] = e / s;
  }
  // MFMA B-operand weight fragments, bf16, layout [c][mat][lane][j]
  for (int i = tid; i < 6144; i += 1024) {
    int j = i & 7, l = (i >> 3) & 63, cm = i >> 9;
    int c = cm >> 1, mat = cm & 1;
    int h = l >> 5, nn = l & 31;
    int d = 16 * c + 8 * h + j;
    float v = 0.0f;
    if (d < D_) {
      float ivd = expf(-lv[nn * D_ + d]);
      v = (mat == 0) ? -0.5f * ivd : mu[nn * D_ + d] * ivd;
    }
    ((ushort*)(ws + WS_WF))[i] = (ushort)((__float_as_uint(v) + 0x8000u) >> 16);
  }
  if (tid < 32) {  // c0[k] = -0.5*(sum mu^2*iv + sum lv + D*log(2pi))
    float s = 0.0f;
    for (int d = 0; d < D_; ++d) {
      float l  = lv[tid * D_ + d];
      float iv = expf(-l);
      float m_ = mu[tid * D_ + d];
      s += m_ * m_ * iv + l;
    }
    ws[WS_C0 + tid] = -0.5f * (s + (float)D_ * 1.8378770664093453f);
  }
}

// ---------------- fused: emission MFMA -> E in LDS -> chunk recursion ----------------
// Block = 128 consecutive t of one b; wave w owns 32 t = exactly one chunk.
// E never touches HBM. E region ALIASES the (dead-by-then) X staging region:
// per wave, all X reads (emission c-loop) complete before the first E write, and
// regions are wave-private, so one 26.6 KB buffer suffices -> 6 blocks/CU (was 3).
__global__ __launch_bounds__(256, 6) void fused_kernel(const float* __restrict__ X,
                                                       float* __restrict__ ws) {
  __shared__ ushort sh[4][32 * 104];   // 26.6 KB total: X rows (stride 104);
                                       // E tile (stride 40) overlays front after use
  int tid = threadIdx.x;
  int l = tid & 63, w = tid >> 6;
  int n = l & 31, h = l >> 5;
  int tB = blockIdx.x << 7;
  // ---- stage X as rounded bf16 (pairs never straddle rows: 90 is even) ----
  const float4* Xg = (const float4*)(X + (size_t)tB * D_);
  #pragma unroll
  for (int it = 0; it < 12; ++it) {
    int i = tid + (it << 8);
    if (i < 2880) {
      float4 v = Xg[i];
      int g = i / 720;
      int f = (i - g * 720) * 4;          // float index within 32-row group
      uint32_t d0 = rnd_pk(v.y, v.x);
      uint32_t d1 = rnd_pk(v.w, v.z);
      int r0 = f / 90;        int c0_ = f - r0 * 90;
      int r1 = (f + 2) / 90;  int c1_ = (f + 2) - r1 * 90;
      *(uint32_t*)&sh[g][r0 * 104 + c0_] = d0;
      *(uint32_t*)&sh[g][r1 * 104 + c1_] = d1;
    }
  }
  for (int i = tid; i < 896; i += 256) {  // zero the d=90..103 pad (weights are 0 there,
    int r = i / 7;                        // but garbage bf16 could be NaN: NaN*0=NaN)
    int d = 90 + 2 * (i - r * 7);
    *(uint32_t*)&sh[r >> 5][(r & 31) * 104 + d] = 0u;
  }
  const uint4* wfp = (const uint4*)((const ushort*)(ws + WS_WF));
  uint4 wf[12];
  #pragma unroll
  for (int cm = 0; cm < 12; ++cm) wf[cm] = wfp[cm * 64 + l];   // coalesced b128
  float c0 = ws[WS_C0 + n];
  __syncthreads();

  int t0 = tB + (w << 5);
  int b  = t0 >> 12;
  int bc = t0 >> 5;                       // global chunk index = b*128 + c
  const ushort* xrow = &sh[w][n * 104];   // A-row m = n
  f32x16 acc1, acc2;
  #pragma unroll
  for (int r = 0; r < 16; ++r) { acc1[r] = 0.0f; acc2[r] = 0.0f; }
  #pragma unroll
  for (int c = 0; c < 6; ++c) {
    union { uint4 u; bf16x8 v; } xb;
    xb.u = *(const uint4*)(xrow + 16 * c + 8 * h);   // b128, A-frag ready
    float x[8];
    #pragma unroll
    for (int j = 0; j < 8; ++j) {
      uint32_t uu = ((const uint32_t*)&xb.u)[j >> 1];
      x[j] = bf2f((j & 1) ? (ushort)(uu >> 16) : (ushort)(uu & 0xFFFF));
    }
    union { uint32_t u[4]; bf16x8 v; } x2b;
    #pragma unroll
    for (int r = 0; r < 4; ++r)
      x2b.u[r] = rnd_pk(x[2*r+1] * x[2*r+1], x[2*r] * x[2*r]);
    union { uint4 u; bf16x8 v; } w2, w1;
    w2.u = wf[c * 2]; w1.u = wf[c * 2 + 1];
    acc1 = __builtin_amdgcn_mfma_f32_32x32x16_bf16(xb.v,  w1.v, acc1, 0, 0, 0);
    acc2 = __builtin_amdgcn_mfma_f32_32x32x16_bf16(x2b.v, w2.v, acc2, 0, 0, 0);
  }
  // C/D: col k = n, row t = (r&3) + 8*(r>>2) + 4*h
  float em[16], mrow[16];
  #pragma unroll
  for (int r = 0; r < 16; ++r) {
    float v = acc1[r] + acc2[r] + c0;
    em[r] = v;
    float m = v;
    #pragma unroll
    for (int mk = 1; mk <= 16; mk <<= 1) m = fmaxf(m, __shfl_xor(m, mk));  // max over k
    mrow[r] = m;
  }
  // E[k][t] tile, stride 40 ushorts, overlays the (now dead) X rows of this wave.
  // Same shared array => compiler preserves in-wave ds ordering (X reads precede).
  ushort* Ew = sh[w];
  #pragma unroll
  for (int q = 0; q < 4; ++q) {
    float e0 = exp2f((em[4*q]   - mrow[4*q])   * 1.44269504088896f);
    float e1 = exp2f((em[4*q+1] - mrow[4*q+1]) * 1.44269504088896f);
    float e2 = exp2f((em[4*q+2] - mrow[4*q+2]) * 1.44269504088896f);
    float e3 = exp2f((em[4*q+3] - mrow[4*q+3]) * 1.44269504088896f);
    uint2 d;
    d.x = rnd_pk(e1, e0);
    d.y = rnd_pk(e3, e2);
    *(uint2*)(Ew + n * 40 + 8 * q + 4 * h) = d;
    if (q == 0 && h == 0 && (t0 & (T_ - 1)) == 0)   // export E[b][k][0] for alpha0
      ((ushort*)(ws + WS_E0))[b * K_ + n] = (ushort)(d.x & 0xFFFF);
  }
  float msum = 0.0f;
  #pragma unroll
  for (int r = 0; r < 16; ++r) msum += mrow[r];
  msum += __shfl_xor(msum, 32);
  if (l == 0) ws[WS_MS + bc] = msum;
  // no barrier: E tile is wave-private, in-wave lgkmcnt ordering suffices

  // ---- chunk recursion (wave-local E from LDS) ----
  int col = perm_r(n);                    // logical output-state of this lane's A column
  const float* A = ws + WS_A;
  float astat[16];
  #pragma unroll
  for (int j = 0; j < 8; ++j) {
    astat[j]     = A[(8 * h + j) * K_ + col];
    astat[8 + j] = A[(16 + 8 * h + j) * K_ + col];
  }
  uint32_t q[8];                          // Q fragments (bf16x2 dwords), init = I
  #pragma unroll
  for (int r = 0; r < 4; ++r) {
    int s0 = 8 * h + 2 * r;
    uint32_t lo = (s0 == n)     ? 0x3F80u : 0u;
    uint32_t hi = (s0 + 1 == n) ? 0x3F80u : 0u;
    q[r] = lo | (hi << 16);
    int s2 = s0 + 16;
    lo = (s2 == n)     ? 0x3F80u : 0u;
    hi = (s2 + 1 == n) ? 0x3F80u : 0u;
    q[4 + r] = lo | (hi << 16);
  }
  int eacc = 0;
  const f32x16 z = {0.f,0.f,0.f,0.f,0.f,0.f,0.f,0.f,0.f,0.f,0.f,0.f,0.f,0.f,0.f,0.f};
  f32x16 acc;
  #pragma unroll
  for (int r = 0; r < 16; ++r) acc[r] = 0.0f;

  auto step = [&](float e0) {
    uint32_t au[8];
    #pragma unroll
    for (int r = 0; r < 4; ++r) {         // A-frag = astat * E[col], truncated to bf16
      au[r]     = pk2(astat[2 * r + 1] * e0, astat[2 * r] * e0);
      au[4 + r] = pk2(astat[8 + 2 * r + 1] * e0, astat[8 + 2 * r] * e0);
    }
    bf16x8 alo = mkbf(au[0], au[1], au[2], au[3]);
    bf16x8 ahi = mkbf(au[4], au[5], au[6], au[7]);
    bf16x8 qlo = mkbf(q[0], q[1], q[2], q[3]);
    bf16x8 qhi = mkbf(q[4], q[5], q[6], q[7]);
    acc = __builtin_amdgcn_mfma_f32_32x32x16_bf16(alo, qlo, z, 0, 0, 0);
    acc = __builtin_amdgcn_mfma_f32_32x32x16_bf16(ahi, qhi, acc, 0, 0, 0);
    #pragma unroll
    for (int r = 0; r < 4; ++r) {         // D regs -> next B-frag, in-lane repack only
      q[r]     = pk2(acc[2 * r + 1], acc[2 * r]);
      q[4 + r] = pk2(acc[8 + 2 * r + 1], acc[8 + 2 * r]);
    }
  };
  auto renorm = [&]() {                   // exact power-of-2 renormalization
    float m = acc[0];
    #pragma unroll
    for (int r = 1; r < 16; ++r) m = fmaxf(m, acc[r]);
    #pragma unroll
    for (int mk = 1; mk <= 32; mk <<= 1) m = fmaxf(m, __shfl_xor(m, mk));
    int ex;
    frexpf(m, &ex);
    float sc = ldexpf(1.0f, -ex);
    eacc += ex;
    #pragma unroll
    for (int r = 0; r < 16; ++r) acc[r] *= sc;
    #pragma unroll
    for (int r = 0; r < 4; ++r) {
      q[r]     = pk2(acc[2 * r + 1], acc[2 * r]);
      q[4 + r] = pk2(acc[8 + 2 * r + 1], acc[8 + 2 * r]);
    }
  };

  const ushort* Eb = sh[w] + col * 40;
  int g0 = 0;
  if ((t0 & (T_ - 1)) == 0) {             // t=0 is the prior step: skip it
    uint4 ev = *(const uint4*)(Eb);
    #pragma unroll
    for (int j = 1; j < 8; ++j) {
      uint32_t u = ((const uint32_t*)&ev)[j >> 1];
      step(bf2f((j & 1) ? (ushort)(u >> 16) : (ushort)(u & 0xFFFF)));
    }
    renorm();
    g0 = 1;
  }
  for (int g = g0; g < CH_ / 8; ++g) {
    uint4 ev = *(const uint4*)(Eb + 8 * g);
    #pragma unroll
    for (int j = 0; j < 8; ++j) {
      uint32_t u = ((const uint32_t*)&ev)[j >> 1];
      step(bf2f((j & 1) ? (ushort)(u >> 16) : (ushort)(u & 0xFFFF)));
    }
    renorm();
  }
  // store Q as bf16 TRUNCATED == the pk2 the combine applies: bit-identical inputs
  ushort* Qo = (ushort*)(ws + WS_Q) + (size_t)bc * (K_ * K_);
  #pragma unroll
  for (int r = 0; r < 16; ++r) {          // row = pi(physical row), col = n
    int m_ = (r & 3) + 8 * (r >> 2) + 4 * h;
    Qo[perm_r(m_) * K_ + n] = (ushort)(__float_as_uint(acc[r]) >> 16);
  }
  if (l == 0) ((int*)ws)[WS_EACC + bc] = eacc;
}

// ---------------- combine stage 1: 512 one-wave blocks (spread Q read over all CUs) ----
__global__ __launch_bounds__(64) void combine1_kernel(float* __restrict__ ws) {
  int l = threadIdx.x;
  int h = l >> 5, n = l & 31;
  int bw = blockIdx.x;                    // b*8 + w
  int b = bw >> 3, w = bw & 7;
  int row = perm_r(n);
  const ushort* Qb = (const ushort*)(ws + WS_Q) + (size_t)(b * F_ + w * 16) * (K_ * K_);
  int eacc;
  {
    const int* ea = ((const int*)ws) + WS_EACC + b * F_ + w * 16;
    int v = (l < 16) ? ea[l] : 0;
    #pragma unroll
    for (int mk = 1; mk <= 8; mk <<= 1) v += __shfl_xor(v, mk);
    eacc = __shfl(v, 0);
  }
  uint32_t q[8];                          // B-frag = identity
  #pragma unroll
  for (int r = 0; r < 4; ++r) {
    int s0 = 8 * h + 2 * r;
    uint32_t lo = (s0 == n)     ? 0x3F80u : 0u;
    uint32_t hi = (s0 + 1 == n) ? 0x3F80u : 0u;
    q[r] = lo | (hi << 16);
    int s2 = s0 + 16;
    lo = (s2 == n)     ? 0x3F80u : 0u;
    hi = (s2 + 1 == n) ? 0x3F80u : 0u;
    q[4 + r] = lo | (hi << 16);
  }
  f32x16 acc;
  #pragma unroll
  for (int r = 0; r < 16; ++r) acc[r] = 0.0f;
  const f32x16 z = {0.f,0.f,0.f,0.f,0.f,0.f,0.f,0.f,0.f,0.f,0.f,0.f,0.f,0.f,0.f,0.f};

  auto lmul = [&](uint4 lo, uint4 hi) {   // A-frags come straight from memory (bf16)
    bf16x8 alo = mkbf(lo.x, lo.y, lo.z, lo.w);
    bf16x8 ahi = mkbf(hi.x, hi.y, hi.z, hi.w);
    bf16x8 qlo = mkbf(q[0], q[1], q[2], q[3]);
    bf16x8 qhi = mkbf(q[4], q[5], q[6], q[7]);
    acc = __builtin_amdgcn_mfma_f32_32x32x16_bf16(alo, qlo, z, 0, 0, 0);
    acc = __builtin_amdgcn_mfma_f32_32x32x16_bf16(ahi, qhi, acc, 0, 0, 0);
    #pragma unroll
    for (int r = 0; r < 4; ++r) {
      q[r]     = pk2(acc[2 * r + 1], acc[2 * r]);
      q[4 + r] = pk2(acc[8 + 2 * r + 1], acc[8 + 2 * r]);
    }
  };
  auto renorm = [&]() {
    float m = acc[0];
    #pragma unroll
    for (int r = 1; r < 16; ++r) m = fmaxf(m, acc[r]);
    #pragma unroll
    for (int mk = 1; mk <= 32; mk <<= 1) m = fmaxf(m, __shfl_xor(m, mk));
    int ex;
    frexpf(m, &ex);
    float sc = ldexpf(1.0f, -ex);
    eacc += ex;
    #pragma unroll
    for (int r = 0; r < 16; ++r) acc[r] *= sc;
    #pragma unroll
    for (int r = 0; r < 4; ++r) {
      q[r]     = pk2(acc[2 * r + 1], acc[2 * r]);
      q[4 + r] = pk2(acc[8 + 2 * r + 1], acc[8 + 2 * r]);
    }
  };

  uint4 rlo[4], rhi[4];                   // depth-4 prefetch ring, static indices only
  #pragma unroll
  for (int p = 0; p < 4; ++p) {
    const ushort* Mc = Qb + (size_t)p * (K_ * K_) + row * K_;
    rlo[p] = *(const uint4*)(Mc + 8 * h);
    rhi[p] = *(const uint4*)(Mc + 16 + 8 * h);
  }
  #pragma unroll
  for (int c = 0; c < 16; ++c) {          // ascending c => later chunks on the left
    lmul(rlo[c & 3], rhi[c & 3]);
    if (c + 4 < 16) {
      const ushort* Mc = Qb + (size_t)(c + 4) * (K_ * K_) + row * K_;
      rlo[c & 3] = *(const uint4*)(Mc + 8 * h);
      rhi[c & 3] = *(const uint4*)(Mc + 16 + 8 * h);
    }
    if ((c & 3) == 3) renorm();
  }
  // publish partial product, bf16 A-frag truncated (bit-identical to fused's Q store)
  ushort* pmq = (ushort*)(ws + WS_PM) + (size_t)bw * (K_ * K_);
  #pragma unroll
  for (int r = 0; r < 16; ++r) {
    int m_ = (r & 3) + 8 * (r >> 2) + 4 * h;
    pmq[perm_r(m_) * K_ + n] = (ushort)(__float_as_uint(acc[r]) >> 16);
  }
  if (l == 0) ((int*)ws)[WS_PE + bw] = eacc;
}

// ---------------- combine stage 2: compose 8 partials per b + alpha0 ----------------
__global__ __launch_bounds__(64) void combine2_kernel(float* __restrict__ ws,
                                                      float* __restrict__ out) {
  int l = threadIdx.x;
  int h = l >> 5, n = l & 31;
  int b = blockIdx.x;
  int row = perm_r(n);
  float alpha0 = ws[WS_PI + n] * bf2f(((const ushort*)(ws + WS_E0))[b * K_ + n]);
  float msm = ws[WS_MS + b * 128 + l] + ws[WS_MS + b * 128 + 64 + l];
  uint32_t q[8];
  #pragma unroll
  for (int r = 0; r < 4; ++r) {
    int s0 = 8 * h + 2 * r;
    uint32_t lo = (s0 == n)     ? 0x3F80u : 0u;
    uint32_t hi = (s0 + 1 == n) ? 0x3F80u : 0u;
    q[r] = lo | (hi << 16);
    int s2 = s0 + 16;
    lo = (s2 == n)     ? 0x3F80u : 0u;
    hi = (s2 + 1 == n) ? 0x3F80u : 0u;
    q[4 + r] = lo | (hi << 16);
  }
  f32x16 acc;
  #pragma unroll
  for (int r = 0; r < 16; ++r) acc[r] = 0.0f;
  const f32x16 z = {0.f,0.f,0.f,0.f,0.f,0.f,0.f,0.f,0.f,0.f,0.f,0.f,0.f,0.f,0.f,0.f};
  const ushort* pmq = (const ushort*)(ws + WS_PM) + (size_t)b * 8 * (K_ * K_);
  #pragma unroll
  for (int p = 0; p < 8; ++p) {           // no renorm: drift <= 2^±40, fp32-safe
    const ushort* base = pmq + p * (K_ * K_) + row * K_;
    uint4 lo = *(const uint4*)(base + 8 * h);
    uint4 hi = *(const uint4*)(base + 16 + 8 * h);
    bf16x8 alo = mkbf(lo.x, lo.y, lo.z, lo.w);
    bf16x8 ahi = mkbf(hi.x, hi.y, hi.z, hi.w);
    bf16x8 qlo = mkbf(q[0], q[1], q[2], q[3]);
    bf16x8 qhi = mkbf(q[4], q[5], q[6], q[7]);
    acc = __builtin_amdgcn_mfma_f32_32x32x16_bf16(alo, qlo, z, 0, 0, 0);
    acc = __builtin_amdgcn_mfma_f32_32x32x16_bf16(ahi, qhi, acc, 0, 0, 0);
    #pragma unroll
    for (int r = 0; r < 4; ++r) {
      q[r]     = pk2(acc[2 * r + 1], acc[2 * r]);
      q[4 + r] = pk2(acc[8 + 2 * r + 1], acc[8 + 2 * r]);
    }
  }
  int et = (l < 8) ? ((const int*)ws)[WS_PE + b * 8 + l] : 0;
  #pragma unroll
  for (int mk = 1; mk <= 4; mk <<= 1) et += __shfl_xor(et, mk);
  et = __shfl(et, 0);
  // ssum = sum_{k,j} Qtot[k][j] * alpha0[j]; lane holds col n, rows across (r,h)
  float part = 0.0f;
  #pragma unroll
  for (int r = 0; r < 16; ++r) part += acc[r];
  part *= alpha0;
  #pragma unroll
  for (int mk = 1; mk <= 32; mk <<= 1) part += __shfl_xor(part, mk);
  #pragma unroll
  for (int mk = 32; mk; mk >>= 1) msm += __shfl_xor(msm, mk);
  if (l == 0) {
    float res = logf(part) + (float)et * 0.69314718055994531f + msm;
    atomicAdd(out, res);
  }
}

extern "C" void kernel_launch(void* const* d_in, const int* in_sizes, int n_in,
                              void* d_out, int out_size, void* d_ws, size_t ws_size,
                              hipStream_t stream) {
  (void)in_sizes; (void)n_in; (void)out_size; (void)ws_size;
  const float* X      = (const float*)d_in[0];
  const float* priors = (const float*)d_in[1];
  const float* trans  = (const float*)d_in[2];
  const float* mu     = (const float*)d_in[3];
  const float* lv     = (const float*)d_in[4];
  float* ws  = (float*)d_ws;
  float* out = (float*)d_out;
  hipMemsetAsync(out, 0, sizeof(float), stream);
  prep_kernel<<<1, 1024, 0, stream>>>(priors, trans, mu, lv, ws);
  fused_kernel<<<B_ * T_ / 128, 256, 0, stream>>>(X, ws);
  combine1_kernel<<<B_ * 8, 64, 0, stream>>>(ws);
  combine2_kernel<<<B_, 64, 0, stream>>>(ws, out);
}